// Round 1
// baseline (121.199 us; speedup 1.0000x reference)
//
#include <hip/hip_runtime.h>

#define N_NODES 100000
#define DEG 16
#define N_EDGES (N_NODES * DEG)
#define NBLK_EDGE (N_EDGES / 256)   // 6250 exactly

// ---------------------------------------------------------------------------
// Kernel 1: per-node matvecs.
//   AB[n][0:64]   = W0[:, 0:64]  @ f[n] + b0     (A-part, b0 folded)
//   AB[n][64:128] = W0[:, 64:128]@ f[n]          (B-part)
// Tile: 64 nodes x 128 outs per block of 256 threads; 8 nodes x 4 outs per thread.
// ---------------------------------------------------------------------------
__global__ __launch_bounds__(256) void k_ab(const float* __restrict__ feat,
                                            const float* __restrict__ w0,
                                            const float* __restrict__ b0,
                                            float* __restrict__ AB) {
    __shared__ float ws[64][128];   // ws[k][o] = W0 transposed (o<64: A cols, o>=64: B cols)
    __shared__ float fs[64][64];    // feature tile
    const int tid = threadIdx.x;

    for (int idx = tid; idx < 64 * 128; idx += 256) {
        int k = idx >> 7, o = idx & 127;
        ws[k][o] = (o < 64) ? w0[o * 129 + k] : w0[(o - 64) * 129 + 64 + k];
    }
    const int n0 = blockIdx.x * 64;
    for (int idx = tid; idx < 1024; idx += 256) {     // 1024 float4s = 64x64 floats
        int flat = idx << 2;
        int nn = flat >> 6, k = flat & 63;
        int n = n0 + nn;
        float4 v = make_float4(0.f, 0.f, 0.f, 0.f);
        if (n < N_NODES) v = *(const float4*)(feat + (size_t)n * 64 + k);
        *(float4*)&fs[nn][k] = v;
    }
    __syncthreads();

    const int to = tid & 31;   // output group: 4 outs
    const int tn = tid >> 5;   // node group: 8 nodes
    float acc[8][4];
#pragma unroll
    for (int a = 0; a < 8; ++a) {
        acc[a][0] = 0.f; acc[a][1] = 0.f; acc[a][2] = 0.f; acc[a][3] = 0.f;
    }
#pragma unroll 2
    for (int k = 0; k < 64; k += 4) {
        float4 w40 = *(const float4*)&ws[k + 0][to * 4];
        float4 w41 = *(const float4*)&ws[k + 1][to * 4];
        float4 w42 = *(const float4*)&ws[k + 2][to * 4];
        float4 w43 = *(const float4*)&ws[k + 3][to * 4];
#pragma unroll
        for (int a = 0; a < 8; ++a) {
            float4 f4 = *(const float4*)&fs[tn * 8 + a][k];
            acc[a][0] = fmaf(f4.x, w40.x, acc[a][0]);
            acc[a][1] = fmaf(f4.x, w40.y, acc[a][1]);
            acc[a][2] = fmaf(f4.x, w40.z, acc[a][2]);
            acc[a][3] = fmaf(f4.x, w40.w, acc[a][3]);
            acc[a][0] = fmaf(f4.y, w41.x, acc[a][0]);
            acc[a][1] = fmaf(f4.y, w41.y, acc[a][1]);
            acc[a][2] = fmaf(f4.y, w41.z, acc[a][2]);
            acc[a][3] = fmaf(f4.y, w41.w, acc[a][3]);
            acc[a][0] = fmaf(f4.z, w42.x, acc[a][0]);
            acc[a][1] = fmaf(f4.z, w42.y, acc[a][1]);
            acc[a][2] = fmaf(f4.z, w42.z, acc[a][2]);
            acc[a][3] = fmaf(f4.z, w42.w, acc[a][3]);
            acc[a][0] = fmaf(f4.w, w43.x, acc[a][0]);
            acc[a][1] = fmaf(f4.w, w43.y, acc[a][1]);
            acc[a][2] = fmaf(f4.w, w43.z, acc[a][2]);
            acc[a][3] = fmaf(f4.w, w43.w, acc[a][3]);
        }
    }
    float4 bb = make_float4(0.f, 0.f, 0.f, 0.f);
    if (to < 16) bb = *(const float4*)(b0 + to * 4);   // fold b0 into A-part only
#pragma unroll
    for (int a = 0; a < 8; ++a) {
        int n = n0 + tn * 8 + a;
        if (n < N_NODES) {
            float4 o4 = make_float4(acc[a][0] + bb.x, acc[a][1] + bb.y,
                                    acc[a][2] + bb.z, acc[a][3] + bb.w);
            *(float4*)(AB + (size_t)n * 128 + to * 4) = o4;
        }
    }
}

// ---------------------------------------------------------------------------
// Kernel 2: per-edge z = b1 + sum_j w1[j]*relu(A[row][j] + B[col][j] + w0v[j]*v)
// plus deterministic per-block fp64 sum of z^2.
// w0/w1 accesses are wave-uniform -> scalar loads (SMEM path), no LDS needed.
// ---------------------------------------------------------------------------
__global__ __launch_bounds__(256) void k_edge(const float* __restrict__ AB,
                                              const float* __restrict__ values,
                                              const int* __restrict__ indices,
                                              const float* __restrict__ w0,
                                              const float* __restrict__ w1,
                                              const float* __restrict__ b1,
                                              float* __restrict__ z,
                                              double* __restrict__ partial) {
    __shared__ double red[256];
    const int t = threadIdx.x;
    const int e = blockIdx.x * 256 + t;        // grid exact: no guard needed
    const int row = indices[e];
    const int col = indices[N_EDGES + e];
    const float v = values[e];
    const float* Ap = AB + (size_t)row * 128;
    const float* Bp = AB + (size_t)col * 128 + 64;
    float acc = 0.f;
#pragma unroll
    for (int q = 0; q < 16; ++q) {
        float4 a4 = *(const float4*)(Ap + q * 4);
        float4 b4 = *(const float4*)(Bp + q * 4);
        float t0 = fmaf(w0[(q * 4 + 0) * 129 + 128], v, a4.x + b4.x);
        float t1 = fmaf(w0[(q * 4 + 1) * 129 + 128], v, a4.y + b4.y);
        float t2 = fmaf(w0[(q * 4 + 2) * 129 + 128], v, a4.z + b4.z);
        float t3 = fmaf(w0[(q * 4 + 3) * 129 + 128], v, a4.w + b4.w);
        acc = fmaf(w1[q * 4 + 0], fmaxf(t0, 0.f), acc);
        acc = fmaf(w1[q * 4 + 1], fmaxf(t1, 0.f), acc);
        acc = fmaf(w1[q * 4 + 2], fmaxf(t2, 0.f), acc);
        acc = fmaf(w1[q * 4 + 3], fmaxf(t3, 0.f), acc);
    }
    const float zz = acc + b1[0];
    z[e] = zz;
    red[t] = (double)zz * (double)zz;
    __syncthreads();
#pragma unroll
    for (int off = 128; off > 0; off >>= 1) {
        if (t < off) red[t] += red[t + off];
        __syncthreads();
    }
    if (t == 0) partial[blockIdx.x] = red[0];
}

// ---------------------------------------------------------------------------
// Kernel 3: deterministic fp64 reduction of block partials -> max(||z||, 1e-12)
// ---------------------------------------------------------------------------
__global__ __launch_bounds__(256) void k_norm(const double* __restrict__ partial,
                                              double* __restrict__ nrm) {
    __shared__ double red[256];
    const int t = threadIdx.x;
    double s = 0.0;
    for (int i = t; i < NBLK_EDGE; i += 256) s += partial[i];
    red[t] = s;
    __syncthreads();
#pragma unroll
    for (int off = 128; off > 0; off >>= 1) {
        if (t < off) red[t] += red[t + off];
        __syncthreads();
    }
    if (t == 0) nrm[0] = fmax(sqrt(red[0]), 1e-12);
}

// ---------------------------------------------------------------------------
// Kernel 4: per-node (thread-per-node, 16 edges each), all math in fp64:
//   zn = z/||z||; pi = softmax(zn); l = (log(pi)+g)/T; y = softmax(l);
//   thre = 8th largest y; out = (y - thre + 1e-12 > 0) ? y : 0
// Count-based order statistic keeps everything statically indexed (registers).
// ---------------------------------------------------------------------------
__global__ __launch_bounds__(256) void k_mask(const float* __restrict__ z,
                                              const float* __restrict__ gumbel,
                                              const double* __restrict__ nrm,
                                              const int* __restrict__ temperature,
                                              float* __restrict__ out) {
    const int n = blockIdx.x * 256 + threadIdx.x;
    if (n >= N_NODES) return;
    const double nv = nrm[0];
    const double T = (double)temperature[0];
    const float4* z4 = (const float4*)(z + (size_t)n * 16);
    const float4* g4 = (const float4*)(gumbel + (size_t)n * 16);
    double a[16], b[16], l[16];
#pragma unroll
    for (int q = 0; q < 4; ++q) {
        float4 v = z4[q];
        a[q * 4 + 0] = (double)v.x / nv;
        a[q * 4 + 1] = (double)v.y / nv;
        a[q * 4 + 2] = (double)v.z / nv;
        a[q * 4 + 3] = (double)v.w / nv;
    }
    double m1 = a[0];
#pragma unroll
    for (int i = 1; i < 16; ++i) m1 = fmax(m1, a[i]);
    double s1 = 0.0;
#pragma unroll
    for (int i = 0; i < 16; ++i) { b[i] = exp(a[i] - m1); s1 += b[i]; }
#pragma unroll
    for (int q = 0; q < 4; ++q) {
        float4 v = g4[q];
        l[q * 4 + 0] = (log(b[q * 4 + 0] / s1) + (double)v.x) / T;
        l[q * 4 + 1] = (log(b[q * 4 + 1] / s1) + (double)v.y) / T;
        l[q * 4 + 2] = (log(b[q * 4 + 2] / s1) + (double)v.z) / T;
        l[q * 4 + 3] = (log(b[q * 4 + 3] / s1) + (double)v.w) / T;
    }
    double m2 = l[0];
#pragma unroll
    for (int i = 1; i < 16; ++i) m2 = fmax(m2, l[i]);
    double s2 = 0.0;
#pragma unroll
    for (int i = 0; i < 16; ++i) { b[i] = exp(l[i] - m2); s2 += b[i]; }
#pragma unroll
    for (int i = 0; i < 16; ++i) a[i] = b[i] / s2;   // y
    // 8th-largest (descending position 7) via strict-greater / equal counts
    double thre = a[0];
#pragma unroll
    for (int i = 0; i < 16; ++i) {
        int c = 0, q = 0;
#pragma unroll
        for (int j = 0; j < 16; ++j) {
            c += (a[j] > a[i]) ? 1 : 0;
            q += (a[j] == a[i]) ? 1 : 0;
        }
        if (c <= 7 && 7 < c + q) thre = a[i];
    }
    float4* o4 = (float4*)(out + (size_t)n * 16);
#pragma unroll
    for (int qq = 0; qq < 4; ++qq) {
        float4 ov;
        ov.x = ((a[qq * 4 + 0] - thre + 1e-12) > 0.0) ? (float)a[qq * 4 + 0] : 0.f;
        ov.y = ((a[qq * 4 + 1] - thre + 1e-12) > 0.0) ? (float)a[qq * 4 + 1] : 0.f;
        ov.z = ((a[qq * 4 + 2] - thre + 1e-12) > 0.0) ? (float)a[qq * 4 + 2] : 0.f;
        ov.w = ((a[qq * 4 + 3] - thre + 1e-12) > 0.0) ? (float)a[qq * 4 + 3] : 0.f;
        o4[qq] = ov;
    }
}

// ---------------------------------------------------------------------------
extern "C" void kernel_launch(void* const* d_in, const int* in_sizes, int n_in,
                              void* d_out, int out_size, void* d_ws, size_t ws_size,
                              hipStream_t stream) {
    const float* feat    = (const float*)d_in[0];   // [N,64]
    const float* values  = (const float*)d_in[1];   // [E]
    const float* w0      = (const float*)d_in[2];   // [64,129]
    const float* b0      = (const float*)d_in[3];   // [64]
    const float* w1      = (const float*)d_in[4];   // [1,64]
    const float* b1      = (const float*)d_in[5];   // [1]
    const float* gumbel  = (const float*)d_in[6];   // [E]
    const int*   indices = (const int*)d_in[7];     // [2,E]
    const int*   temp    = (const int*)d_in[9];     // scalar
    float* out = (float*)d_out;

    // workspace layout (bytes): AB 51.2e6 | z 6.4e6 | partial 50e3 | nrm 8
    float*  AB      = (float*)d_ws;
    float*  z       = (float*)((char*)d_ws + (size_t)N_NODES * 128 * 4);
    double* partial = (double*)((char*)d_ws + (size_t)N_NODES * 128 * 4 + (size_t)N_EDGES * 4);
    double* nrm     = partial + NBLK_EDGE;

    k_ab  <<<(N_NODES + 63) / 64, 256, 0, stream>>>(feat, w0, b0, AB);
    k_edge<<<NBLK_EDGE, 256, 0, stream>>>(AB, values, indices, w0, w1, b1, z, partial);
    k_norm<<<1, 256, 0, stream>>>(partial, nrm);
    k_mask<<<(N_NODES + 255) / 256, 256, 0, stream>>>(z, gumbel, nrm, temp, out);
}

// Round 2
// 78.783 us; speedup vs baseline: 1.5384x; 1.5384x over previous
//
#include <hip/hip_runtime.h>

#define N_NODES 100000
#define DEG 16
#define N_EDGES (N_NODES * DEG)
#define NT 64                              // nodes per k_edge block
#define NBLK2 ((N_NODES + NT - 1) / NT)    // 1563 edge blocks

// ---------------------------------------------------------------------------
// Kernel 1 (unchanged from round 1): per-node matvecs.
//   AB[n][0:64]   = W0[:, 0:64]  @ f[n] + b0     (A-part, b0 folded)
//   AB[n][64:128] = W0[:, 64:128]@ f[n]          (B-part)
// ---------------------------------------------------------------------------
__global__ __launch_bounds__(256) void k_ab(const float* __restrict__ feat,
                                            const float* __restrict__ w0,
                                            const float* __restrict__ b0,
                                            float* __restrict__ AB) {
    __shared__ float ws[64][128];
    __shared__ float fs[64][64];
    const int tid = threadIdx.x;

    for (int idx = tid; idx < 64 * 128; idx += 256) {
        int k = idx >> 7, o = idx & 127;
        ws[k][o] = (o < 64) ? w0[o * 129 + k] : w0[(o - 64) * 129 + 64 + k];
    }
    const int n0 = blockIdx.x * 64;
    for (int idx = tid; idx < 1024; idx += 256) {
        int flat = idx << 2;
        int nn = flat >> 6, k = flat & 63;
        int n = n0 + nn;
        float4 v = make_float4(0.f, 0.f, 0.f, 0.f);
        if (n < N_NODES) v = *(const float4*)(feat + (size_t)n * 64 + k);
        *(float4*)&fs[nn][k] = v;
    }
    __syncthreads();

    const int to = tid & 31;
    const int tn = tid >> 5;
    float acc[8][4];
#pragma unroll
    for (int a = 0; a < 8; ++a) {
        acc[a][0] = 0.f; acc[a][1] = 0.f; acc[a][2] = 0.f; acc[a][3] = 0.f;
    }
#pragma unroll 2
    for (int k = 0; k < 64; k += 4) {
        float4 w40 = *(const float4*)&ws[k + 0][to * 4];
        float4 w41 = *(const float4*)&ws[k + 1][to * 4];
        float4 w42 = *(const float4*)&ws[k + 2][to * 4];
        float4 w43 = *(const float4*)&ws[k + 3][to * 4];
#pragma unroll
        for (int a = 0; a < 8; ++a) {
            float4 f4 = *(const float4*)&fs[tn * 8 + a][k];
            acc[a][0] = fmaf(f4.x, w40.x, acc[a][0]);
            acc[a][1] = fmaf(f4.x, w40.y, acc[a][1]);
            acc[a][2] = fmaf(f4.x, w40.z, acc[a][2]);
            acc[a][3] = fmaf(f4.x, w40.w, acc[a][3]);
            acc[a][0] = fmaf(f4.y, w41.x, acc[a][0]);
            acc[a][1] = fmaf(f4.y, w41.y, acc[a][1]);
            acc[a][2] = fmaf(f4.y, w41.z, acc[a][2]);
            acc[a][3] = fmaf(f4.y, w41.w, acc[a][3]);
            acc[a][0] = fmaf(f4.z, w42.x, acc[a][0]);
            acc[a][1] = fmaf(f4.z, w42.y, acc[a][1]);
            acc[a][2] = fmaf(f4.z, w42.z, acc[a][2]);
            acc[a][3] = fmaf(f4.z, w42.w, acc[a][3]);
            acc[a][0] = fmaf(f4.w, w43.x, acc[a][0]);
            acc[a][1] = fmaf(f4.w, w43.y, acc[a][1]);
            acc[a][2] = fmaf(f4.w, w43.z, acc[a][2]);
            acc[a][3] = fmaf(f4.w, w43.w, acc[a][3]);
        }
    }
    float4 bb = make_float4(0.f, 0.f, 0.f, 0.f);
    if (to < 16) bb = *(const float4*)(b0 + to * 4);
#pragma unroll
    for (int a = 0; a < 8; ++a) {
        int n = n0 + tn * 8 + a;
        if (n < N_NODES) {
            float4 o4 = make_float4(acc[a][0] + bb.x, acc[a][1] + bb.y,
                                    acc[a][2] + bb.z, acc[a][3] + bb.w);
            *(float4*)(AB + (size_t)n * 128 + to * 4) = o4;
        }
    }
}

// ---------------------------------------------------------------------------
// Kernel 2 (rewritten): LDS-staged edge combine.
// Block = 64 nodes = 1024 edges. cols of node n are (n+1..n+16)%N, so B-part
// rows (n0+1..n0+80)%N are staged contiguously (coalesced); A-part rows
// n0..n0+63 likewise. Thread t owns row t>>2 and its 4 edges 4t..4t+3.
// Per-edge arithmetic is bit-identical to round 1 (same fma order).
// Predicated global fallback if a col is ever outside the staged window.
// ---------------------------------------------------------------------------
__global__ __launch_bounds__(256) void k_edge(const float* __restrict__ AB,
                                              const float* __restrict__ values,
                                              const int* __restrict__ indices,
                                              const float* __restrict__ w0,
                                              const float* __restrict__ w1,
                                              const float* __restrict__ b1,
                                              float* __restrict__ z,
                                              double* __restrict__ partial) {
    __shared__ float a_s[64][68];    // pad 64->68: conflict-free strided reads
    __shared__ float b_s[80][68];
    __shared__ float wv_s[64];       // w0[:,128] (edge-value column)
    __shared__ float w1_s[64];
    __shared__ double red[256];
    const int t = threadIdx.x;
    const int n0 = blockIdx.x * NT;
    const int nvalid = min(NT, N_NODES - n0);

    if (t < 64) {
        wv_s[t] = w0[t * 129 + 128];
        w1_s[t] = w1[t];
    }
    for (int idx = t; idx < 1024; idx += 256) {        // A: 64 rows x 16 float4
        int r = idx >> 4, k4 = idx & 15;
        float4 v = make_float4(0.f, 0.f, 0.f, 0.f);
        if (r < nvalid) v = *(const float4*)(AB + (size_t)(n0 + r) * 128 + k4 * 4);
        *(float4*)&a_s[r][k4 * 4] = v;
    }
    for (int idx = t; idx < 1280; idx += 256) {        // B: 80 rows x 16 float4
        int r = idx >> 4, k4 = idx & 15;
        int node = n0 + 1 + r;
        if (node >= N_NODES) node -= N_NODES;
        *(float4*)&b_s[r][k4 * 4] = *(const float4*)(AB + (size_t)node * 128 + 64 + k4 * 4);
    }
    __syncthreads();

    const int row = t >> 2;
    const bool ok = row < nvalid;
    double ss = 0.0;
    if (ok) {
        const int ebase = n0 * 16 + (t << 2);
        int4   c4 = *(const int4*)(indices + N_EDGES + ebase);
        float4 v4 = *(const float4*)(values + ebase);
        int   cols[4] = {c4.x, c4.y, c4.z, c4.w};
        float vv[4]   = {v4.x, v4.y, v4.z, v4.w};
        int   ii[4];
        bool  fb[4];
        bool  anyfb = false;
#pragma unroll
        for (int k = 0; k < 4; ++k) {
            int i = cols[k] - (n0 + 1);
            if (i < 0) i += N_NODES;
            fb[k] = (i >= 80);
            anyfb |= fb[k];
            ii[k] = fb[k] ? 0 : i;
        }
        float acc[4] = {0.f, 0.f, 0.f, 0.f};
#pragma unroll
        for (int q = 0; q < 16; ++q) {
            float4 a4  = *(const float4*)&a_s[row][q * 4];
            float4 wv4 = *(const float4*)&wv_s[q * 4];
            float4 w14 = *(const float4*)&w1_s[q * 4];
#pragma unroll
            for (int k = 0; k < 4; ++k) {
                float4 b4 = *(const float4*)&b_s[ii[k]][q * 4];
                float t0 = fmaf(wv4.x, vv[k], a4.x + b4.x);
                float t1 = fmaf(wv4.y, vv[k], a4.y + b4.y);
                float t2 = fmaf(wv4.z, vv[k], a4.z + b4.z);
                float t3 = fmaf(wv4.w, vv[k], a4.w + b4.w);
                acc[k] = fmaf(w14.x, fmaxf(t0, 0.f), acc[k]);
                acc[k] = fmaf(w14.y, fmaxf(t1, 0.f), acc[k]);
                acc[k] = fmaf(w14.z, fmaxf(t2, 0.f), acc[k]);
                acc[k] = fmaf(w14.w, fmaxf(t3, 0.f), acc[k]);
            }
        }
        if (anyfb) {            // never taken for this graph; correctness net
#pragma unroll
            for (int k = 0; k < 4; ++k) {
                if (fb[k]) {
                    const float* Bp = AB + (size_t)cols[k] * 128 + 64;
                    float a = 0.f;
                    for (int h = 0; h < 64; ++h) {
                        float th = fmaf(wv_s[h], vv[k], a_s[row][h] + Bp[h]);
                        a = fmaf(w1_s[h], fmaxf(th, 0.f), a);
                    }
                    acc[k] = a;
                }
            }
        }
        const float b1v = b1[0];
        float4 z4;
        z4.x = acc[0] + b1v; z4.y = acc[1] + b1v;
        z4.z = acc[2] + b1v; z4.w = acc[3] + b1v;
        *(float4*)(z + ebase) = z4;
        ss = (double)z4.x * z4.x + (double)z4.y * z4.y +
             (double)z4.z * z4.z + (double)z4.w * z4.w;
    }
    red[t] = ss;
    __syncthreads();
#pragma unroll
    for (int off = 128; off > 0; off >>= 1) {
        if (t < off) red[t] += red[t + off];
        __syncthreads();
    }
    if (t == 0) partial[blockIdx.x] = red[0];
}

// ---------------------------------------------------------------------------
// Kernel 3: deterministic fp64 reduction of block partials -> max(||z||, 1e-12)
// ---------------------------------------------------------------------------
__global__ __launch_bounds__(256) void k_norm(const double* __restrict__ partial,
                                              double* __restrict__ nrm) {
    __shared__ double red[256];
    const int t = threadIdx.x;
    double s = 0.0;
    for (int i = t; i < NBLK2; i += 256) s += partial[i];
    red[t] = s;
    __syncthreads();
#pragma unroll
    for (int off = 128; off > 0; off >>= 1) {
        if (t < off) red[t] += red[t + off];
        __syncthreads();
    }
    if (t == 0) nrm[0] = fmax(sqrt(red[0]), 1e-12);
}

// ---------------------------------------------------------------------------
// Kernel 4 (simplified): y = softmax over each node's 16 of (z/||z|| + g)/T.
// The reference's softmax->log->+gumbel->softmax collapses exactly: the
// per-row constant (-m - log s)/T cancels in the outer softmax. fp64 chain
// kept for rank stability; 16 exp (was 32 exp + 16 log).
// ---------------------------------------------------------------------------
__global__ __launch_bounds__(256) void k_mask(const float* __restrict__ z,
                                              const float* __restrict__ gumbel,
                                              const double* __restrict__ nrm,
                                              const int* __restrict__ temperature,
                                              float* __restrict__ out) {
    const int n = blockIdx.x * 256 + threadIdx.x;
    if (n >= N_NODES) return;
    const double inv_nv = 1.0 / nrm[0];
    const double invT = 1.0 / (double)temperature[0];
    const float4* z4 = (const float4*)(z + (size_t)n * 16);
    const float4* g4 = (const float4*)(gumbel + (size_t)n * 16);
    double tl[16], y[16];
#pragma unroll
    for (int q = 0; q < 4; ++q) {
        float4 zv = z4[q];
        float4 gv = g4[q];
        tl[q * 4 + 0] = ((double)zv.x * inv_nv + (double)gv.x) * invT;
        tl[q * 4 + 1] = ((double)zv.y * inv_nv + (double)gv.y) * invT;
        tl[q * 4 + 2] = ((double)zv.z * inv_nv + (double)gv.z) * invT;
        tl[q * 4 + 3] = ((double)zv.w * inv_nv + (double)gv.w) * invT;
    }
    double m = tl[0];
#pragma unroll
    for (int i = 1; i < 16; ++i) m = fmax(m, tl[i]);
    double s = 0.0;
#pragma unroll
    for (int i = 0; i < 16; ++i) { y[i] = exp(tl[i] - m); s += y[i]; }
    const double inv_s = 1.0 / s;
#pragma unroll
    for (int i = 0; i < 16; ++i) y[i] *= inv_s;
    // 8th-largest (with multiplicity) via strict-greater / equal counts
    double thre = y[0];
#pragma unroll
    for (int i = 0; i < 16; ++i) {
        int c = 0, q = 0;
#pragma unroll
        for (int j = 0; j < 16; ++j) {
            c += (y[j] > y[i]) ? 1 : 0;
            q += (y[j] == y[i]) ? 1 : 0;
        }
        if (c <= 7 && 7 < c + q) thre = y[i];
    }
    float4* o4 = (float4*)(out + (size_t)n * 16);
#pragma unroll
    for (int qq = 0; qq < 4; ++qq) {
        float4 ov;
        ov.x = ((y[qq * 4 + 0] - thre + 1e-12) > 0.0) ? (float)y[qq * 4 + 0] : 0.f;
        ov.y = ((y[qq * 4 + 1] - thre + 1e-12) > 0.0) ? (float)y[qq * 4 + 1] : 0.f;
        ov.z = ((y[qq * 4 + 2] - thre + 1e-12) > 0.0) ? (float)y[qq * 4 + 2] : 0.f;
        ov.w = ((y[qq * 4 + 3] - thre + 1e-12) > 0.0) ? (float)y[qq * 4 + 3] : 0.f;
        o4[qq] = ov;
    }
}

// ---------------------------------------------------------------------------
extern "C" void kernel_launch(void* const* d_in, const int* in_sizes, int n_in,
                              void* d_out, int out_size, void* d_ws, size_t ws_size,
                              hipStream_t stream) {
    const float* feat    = (const float*)d_in[0];   // [N,64]
    const float* values  = (const float*)d_in[1];   // [E]
    const float* w0      = (const float*)d_in[2];   // [64,129]
    const float* b0      = (const float*)d_in[3];   // [64]
    const float* w1      = (const float*)d_in[4];   // [1,64]
    const float* b1      = (const float*)d_in[5];   // [1]
    const float* gumbel  = (const float*)d_in[6];   // [E]
    const int*   indices = (const int*)d_in[7];     // [2,E]
    const int*   temp    = (const int*)d_in[9];     // scalar
    float* out = (float*)d_out;

    // workspace layout (bytes): AB 51.2e6 | z 6.4e6 | partial 1563*8 | nrm 8
    float*  AB      = (float*)d_ws;
    float*  zbuf    = (float*)((char*)d_ws + (size_t)N_NODES * 128 * 4);
    double* partial = (double*)((char*)d_ws + (size_t)N_NODES * 128 * 4 + (size_t)N_EDGES * 4);
    double* nrm     = partial + NBLK2;

    k_ab  <<<(N_NODES + 63) / 64, 256, 0, stream>>>(feat, w0, b0, AB);
    k_edge<<<NBLK2, 256, 0, stream>>>(AB, values, indices, w0, w1, b1, zbuf, partial);
    k_norm<<<1, 256, 0, stream>>>(partial, nrm);
    k_mask<<<(N_NODES + 255) / 256, 256, 0, stream>>>(zbuf, gumbel, nrm, temp, out);
}